// Round 1
// baseline (1371.538 us; speedup 1.0000x reference)
//
#include <hip/hip_runtime.h>
#include <hip/hip_bf16.h>
#include <stdint.h>

// TransformerEncoder on MI355X. B=2,S=2048,D=512,H=8,DH=64,F=2048,L=6.
// bf16 MFMA GEMMs (fp32 accum), fp32 residual/LN/softmax state.

typedef __bf16 bf16x8 __attribute__((ext_vector_type(8)));
typedef float f32x4 __attribute__((ext_vector_type(4)));
typedef unsigned short u16;

#define NB 2
#define NS 2048
#define ND 512
#define NH 8
#define NDH 64
#define NF 2048
#define NL 6

__device__ __forceinline__ u16 f2bf(float f) {
  unsigned u = __float_as_uint(f);
  u += 0x7FFFu + ((u >> 16) & 1u);
  return (u16)(u >> 16);
}

// ---------------- weight convert + transpose: f32 [K,N] -> bf16 [N,K] ------
__global__ __launch_bounds__(256) void wcvt_t(const float* __restrict__ src,
                                              u16* __restrict__ dst,
                                              int K, int N) {
  __shared__ float tile[32][33];
  int l = blockIdx.z;
  const float* s = src + (size_t)l * K * N;
  u16* d = dst + (size_t)l * K * N;
  int k0 = blockIdx.y * 32, n0 = blockIdx.x * 32;
  int tx = threadIdx.x, ty = threadIdx.y;  // 32x8
  for (int i = 0; i < 32; i += 8)
    tile[ty + i][tx] = s[(size_t)(k0 + ty + i) * N + n0 + tx];
  __syncthreads();
  for (int i = 0; i < 32; i += 8)
    d[(size_t)(n0 + ty + i) * K + k0 + tx] = f2bf(tile[tx][ty + i]);
}

// ---------------- LayerNorm: fp32 in, bf16 (or f32) out --------------------
template <int OUT_BF16>
__global__ __launch_bounds__(256) void ln_k(const float* __restrict__ x,
                                            const float* __restrict__ w,
                                            const float* __restrict__ b,
                                            void* __restrict__ out) {
  int row = blockIdx.x;
  int t = threadIdx.x;  // 256 threads, D=512 -> one float2 each
  const float* xr = x + (size_t)row * ND;
  float2 v = ((const float2*)xr)[t];
  float s = v.x + v.y, ss = v.x * v.x + v.y * v.y;
  for (int o = 32; o > 0; o >>= 1) {
    s += __shfl_down(s, o);
    ss += __shfl_down(ss, o);
  }
  __shared__ float rs[4], rss[4];
  if ((t & 63) == 0) { rs[t >> 6] = s; rss[t >> 6] = ss; }
  __syncthreads();
  float S = rs[0] + rs[1] + rs[2] + rs[3];
  float SS = rss[0] + rss[1] + rss[2] + rss[3];
  float mean = S * (1.0f / ND);
  float var = SS * (1.0f / ND) - mean * mean;
  float rstd = rsqrtf(var + 1e-5f);
  float2 wv = ((const float2*)w)[t];
  float2 bv = ((const float2*)b)[t];
  float y0 = (v.x - mean) * rstd * wv.x + bv.x;
  float y1 = (v.y - mean) * rstd * wv.y + bv.y;
  if (OUT_BF16) {
    ushort2 p; p.x = f2bf(y0); p.y = f2bf(y1);
    ((ushort2*)out)[(size_t)row * (ND / 2) + t] = p;
  } else {
    float2 p; p.x = y0; p.y = y1;
    ((float2*)out)[(size_t)row * (ND / 2) + t] = p;
  }
}

// ---------------- GEMM: C[M,N] = A[M,K](bf16) @ Bt[N,K]^T(bf16) + bias -----
// EPI: 0 = bf16 out, 1 = relu -> bf16 out, 2 = +resid -> f32 out
template <int EPI>
__global__ __launch_bounds__(256) void gemm_bt(const u16* __restrict__ A,
                                               const u16* __restrict__ Bt,
                                               const float* __restrict__ bias,
                                               const float* __restrict__ resid,
                                               void* __restrict__ C,
                                               int M, int N, int K) {
  __shared__ u16 la[128 * 32];
  __shared__ u16 lb[128 * 32];
  int bm = blockIdx.y, bn = blockIdx.x;
  int t = threadIdx.x;
  int wave = t >> 6, lane = t & 63, quad = lane >> 4, l15 = lane & 15;
  int wm = (wave >> 1) * 64, wn = (wave & 1) * 64;
  f32x4 acc[4][4] = {};
  int srow = t >> 2, scol = (t & 3) * 8;
  const u16* Ag = A + (size_t)(bm * 128) * K;
  const u16* Bg = Bt + (size_t)(bn * 128) * K;
  for (int k0 = 0; k0 < K; k0 += 32) {
    __syncthreads();
    *(bf16x8*)&la[srow * 32 + scol] =
        *(const bf16x8*)&Ag[(size_t)srow * K + k0 + scol];
    *(bf16x8*)&la[(srow + 64) * 32 + scol] =
        *(const bf16x8*)&Ag[(size_t)(srow + 64) * K + k0 + scol];
    *(bf16x8*)&lb[srow * 32 + scol] =
        *(const bf16x8*)&Bg[(size_t)srow * K + k0 + scol];
    *(bf16x8*)&lb[(srow + 64) * 32 + scol] =
        *(const bf16x8*)&Bg[(size_t)(srow + 64) * K + k0 + scol];
    __syncthreads();
    bf16x8 af[4], bf[4];
#pragma unroll
    for (int i = 0; i < 4; i++)
      af[i] = *(const bf16x8*)&la[(wm + i * 16 + l15) * 32 + quad * 8];
#pragma unroll
    for (int i = 0; i < 4; i++)
      bf[i] = *(const bf16x8*)&lb[(wn + i * 16 + l15) * 32 + quad * 8];
#pragma unroll
    for (int mt = 0; mt < 4; mt++)
#pragma unroll
      for (int nt = 0; nt < 4; nt++)
        acc[mt][nt] = __builtin_amdgcn_mfma_f32_16x16x32_bf16(
            af[mt], bf[nt], acc[mt][nt], 0, 0, 0);
  }
#pragma unroll
  for (int mt = 0; mt < 4; mt++)
#pragma unroll
    for (int nt = 0; nt < 4; nt++) {
      int col = bn * 128 + wn + nt * 16 + l15;
      float bcol = bias[col];
#pragma unroll
      for (int r = 0; r < 4; r++) {
        int row = bm * 128 + wm + mt * 16 + quad * 4 + r;
        float v = acc[mt][nt][r] + bcol;
        if (EPI == 1) v = fmaxf(v, 0.f);
        if (EPI == 2)
          ((float*)C)[(size_t)row * N + col] = v + resid[(size_t)row * N + col];
        else
          ((u16*)C)[(size_t)row * N + col] = f2bf(v);
      }
    }
}

// ---------------- Flash attention ------------------------------------------
// qkv: [B*S, 3*D] bf16 (q|k|v each [H,DH] per token). o: [B*S, D] bf16.
__global__ __launch_bounds__(256) void attn_k(const u16* __restrict__ qkv,
                                              const float* __restrict__ mask,
                                              u16* __restrict__ o) {
  __shared__ u16 kt_s[64 * 64];   // K tile [sk][dh]
  __shared__ u16 vt_s[64 * 72];   // V^T    [dh][sk] (pad 72 keeps 16B align)
  __shared__ u16 p_s[4][16 * 64]; // per-wave P
  int bh = blockIdx.y;
  int b = bh >> 3, h = bh & 7;
  int qt = blockIdx.x;
  int t = threadIdx.x;
  int wave = t >> 6, lane = t & 63, quad = lane >> 4, l15 = lane & 15;

  int qrow = qt * 64 + wave * 16 + l15;
  const u16* qbase = qkv + ((size_t)(b * NS + qrow)) * (3 * ND) + h * NDH;
  bf16x8 qf[2];
  qf[0] = *(const bf16x8*)&qbase[quad * 8];
  qf[1] = *(const bf16x8*)&qbase[32 + quad * 8];

  f32x4 oacc[4] = {};
  float mrow[4], lrow[4];
#pragma unroll
  for (int r = 0; r < 4; r++) { mrow[r] = -1e30f; lrow[r] = 0.f; }

  int srow = t >> 2, seg = t & 3;
  for (int kt0 = 0; kt0 < NS; kt0 += 64) {
    __syncthreads();
    {
      const u16* kg =
          qkv + ((size_t)(b * NS + kt0 + srow)) * (3 * ND) + ND + h * NDH + seg * 16;
      *(bf16x8*)&kt_s[srow * 64 + seg * 16] = *(const bf16x8*)&kg[0];
      *(bf16x8*)&kt_s[srow * 64 + seg * 16 + 8] = *(const bf16x8*)&kg[8];
      const u16* vg =
          qkv + ((size_t)(b * NS + kt0 + srow)) * (3 * ND) + 2 * ND + h * NDH + seg * 16;
      bf16x8 v0 = *(const bf16x8*)&vg[0];
      bf16x8 v1 = *(const bf16x8*)&vg[8];
#pragma unroll
      for (int e = 0; e < 8; e++) {
        vt_s[(seg * 16 + e) * 72 + srow] = ((u16*)&v0)[e];
        vt_s[(seg * 16 + 8 + e) * 72 + srow] = ((u16*)&v1)[e];
      }
    }
    __syncthreads();
    // S = Q @ K^T
    f32x4 sc[4] = {};
#pragma unroll
    for (int nt = 0; nt < 4; nt++) {
      bf16x8 kf0 = *(const bf16x8*)&kt_s[(nt * 16 + l15) * 64 + quad * 8];
      bf16x8 kf1 = *(const bf16x8*)&kt_s[(nt * 16 + l15) * 64 + 32 + quad * 8];
      sc[nt] = __builtin_amdgcn_mfma_f32_16x16x32_bf16(qf[0], kf0, sc[nt], 0, 0, 0);
      sc[nt] = __builtin_amdgcn_mfma_f32_16x16x32_bf16(qf[1], kf1, sc[nt], 0, 0, 0);
    }
    // online softmax (rows quad*4+r, cols nt*16+l15)
    float mnew[4], alpha[4];
#pragma unroll
    for (int r = 0; r < 4; r++) {
      float mx = -1e30f;
#pragma unroll
      for (int nt = 0; nt < 4; nt++) {
        float s = sc[nt][r] * 0.125f + mask[b * NS + kt0 + nt * 16 + l15];
        sc[nt][r] = s;
        mx = fmaxf(mx, s);
      }
      for (int off = 1; off < 16; off <<= 1) mx = fmaxf(mx, __shfl_xor(mx, off));
      mnew[r] = fmaxf(mrow[r], mx);
    }
#pragma unroll
    for (int r = 0; r < 4; r++) {
      alpha[r] = __expf(mrow[r] - mnew[r]);
      float sum = 0.f;
#pragma unroll
      for (int nt = 0; nt < 4; nt++) {
        float p = __expf(sc[nt][r] - mnew[r]);
        sc[nt][r] = p;
        sum += p;
      }
      for (int off = 1; off < 16; off <<= 1) sum += __shfl_xor(sum, off);
      lrow[r] = lrow[r] * alpha[r] + sum;
      mrow[r] = mnew[r];
    }
#pragma unroll
    for (int nt = 0; nt < 4; nt++)
#pragma unroll
      for (int r = 0; r < 4; r++) oacc[nt][r] *= alpha[r];
    // P: C-layout -> LDS -> A-layout (wave-private region, wave-sync only)
    u16* pw = &p_s[wave][0];
#pragma unroll
    for (int nt = 0; nt < 4; nt++)
#pragma unroll
      for (int r = 0; r < 4; r++)
        pw[(quad * 4 + r) * 64 + nt * 16 + l15] = f2bf(sc[nt][r]);
    asm volatile("s_waitcnt lgkmcnt(0)" ::: "memory");
    // O += P @ V
#pragma unroll
    for (int kk = 0; kk < 2; kk++) {
      bf16x8 pf = *(const bf16x8*)&pw[l15 * 64 + kk * 32 + quad * 8];
#pragma unroll
      for (int nt = 0; nt < 4; nt++) {
        bf16x8 vf = *(const bf16x8*)&vt_s[(nt * 16 + l15) * 72 + kk * 32 + quad * 8];
        oacc[nt] = __builtin_amdgcn_mfma_f32_16x16x32_bf16(pf, vf, oacc[nt], 0, 0, 0);
      }
    }
  }
  u16* ob = o + ((size_t)(b * NS) + qt * 64 + wave * 16) * ND + h * NDH;
#pragma unroll
  for (int nt = 0; nt < 4; nt++)
#pragma unroll
    for (int r = 0; r < 4; r++) {
      float v = oacc[nt][r] / lrow[r];
      ob[(size_t)(quad * 4 + r) * ND + nt * 16 + l15] = f2bf(v);
    }
}

// ---------------------------------------------------------------------------
extern "C" void kernel_launch(void* const* d_in, const int* in_sizes, int n_in,
                              void* d_out, int out_size, void* d_ws, size_t ws_size,
                              hipStream_t stream) {
  const float* x = (const float*)d_in[0];
  const float* mask = (const float*)d_in[1];
  const float* ln1w = (const float*)d_in[2];
  const float* ln1b = (const float*)d_in[3];
  const float* in_w = (const float*)d_in[4];
  const float* in_b = (const float*)d_in[5];
  const float* out_w = (const float*)d_in[6];
  const float* out_b = (const float*)d_in[7];
  const float* ln2w = (const float*)d_in[8];
  const float* ln2b = (const float*)d_in[9];
  const float* f1w = (const float*)d_in[10];
  const float* f1b = (const float*)d_in[11];
  const float* f2w = (const float*)d_in[12];
  const float* f2b = (const float*)d_in[13];
  const float* normw = (const float*)d_in[14];
  const float* normb = (const float*)d_in[15];

  char* ws = (char*)d_ws;
  auto carve = [&](size_t bytes) {
    char* p = ws;
    ws += (bytes + 255) & ~(size_t)255;
    return p;
  };
  u16* wq_t = (u16*)carve((size_t)NL * 3 * ND * ND * 2);   // [L][3D][D]
  u16* wo_t = (u16*)carve((size_t)NL * ND * ND * 2);       // [L][D][D]
  u16* w1_t = (u16*)carve((size_t)NL * NF * ND * 2);       // [L][F][D]
  u16* w2_t = (u16*)carve((size_t)NL * ND * NF * 2);       // [L][D][F]
  u16* ybuf = (u16*)carve((size_t)NB * NS * ND * 2);
  u16* qkv = (u16*)carve((size_t)NB * NS * 3 * ND * 2);
  u16* obuf = (u16*)carve((size_t)NB * NS * ND * 2);
  u16* ubuf = (u16*)carve((size_t)NB * NS * NF * 2);
  float* hA = (float*)carve((size_t)NB * NS * ND * 4);
  float* hB = (float*)carve((size_t)NB * NS * ND * 4);

  const int M = NB * NS;  // 4096
  dim3 tb(32, 8);
  wcvt_t<<<dim3(3 * ND / 32, ND / 32, NL), tb, 0, stream>>>(in_w, wq_t, ND, 3 * ND);
  wcvt_t<<<dim3(ND / 32, ND / 32, NL), tb, 0, stream>>>(out_w, wo_t, ND, ND);
  wcvt_t<<<dim3(NF / 32, ND / 32, NL), tb, 0, stream>>>(f1w, w1_t, ND, NF);
  wcvt_t<<<dim3(ND / 32, NF / 32, NL), tb, 0, stream>>>(f2w, w2_t, NF, ND);

  const float* hin = x;
  for (int l = 0; l < NL; l++) {
    ln_k<1><<<M, 256, 0, stream>>>(hin, ln1w + l * ND, ln1b + l * ND, ybuf);
    gemm_bt<0><<<dim3(3 * ND / 128, M / 128), 256, 0, stream>>>(
        ybuf, wq_t + (size_t)l * 3 * ND * ND, in_b + l * 3 * ND, nullptr, qkv,
        M, 3 * ND, ND);
    attn_k<<<dim3(NS / 64, NB * NH), 256, 0, stream>>>(qkv, mask, obuf);
    gemm_bt<2><<<dim3(ND / 128, M / 128), 256, 0, stream>>>(
        obuf, wo_t + (size_t)l * ND * ND, out_b + l * ND, hin, hB, M, ND, ND);
    ln_k<1><<<M, 256, 0, stream>>>(hB, ln2w + l * ND, ln2b + l * ND, ybuf);
    gemm_bt<1><<<dim3(NF / 128, M / 128), 256, 0, stream>>>(
        ybuf, w1_t + (size_t)l * NF * ND, f1b + l * NF, nullptr, ubuf, M, NF, ND);
    gemm_bt<2><<<dim3(ND / 128, M / 128), 256, 0, stream>>>(
        ubuf, w2_t + (size_t)l * ND * NF, f2b + l * ND, hB, hA, M, ND, NF);
    hin = hA;
  }
  ln_k<0><<<M, 256, 0, stream>>>(hA, normw, normb, (float*)d_out);
}